// Round 8
// baseline (239.180 us; speedup 1.0000x reference)
//
#include <hip/hip_runtime.h>

// LinearCRF: mean_b( logZ_b - gold_b ), B=8192, L=1024, S=3.
// R11: ABLATION ROUND. Five falsified single-variable theories (access
// pattern R4/R9, I$ R6/R9, register-cap/MLP R7/R8, cache R6, atomic tail
// R10) all leave the invariant: dur 65us, VALUBusy 27%, occ 31%, and
// VALUBusy*dur == 18-19us constant across ALL variants. Per-wave: ~2.2us
// issue, ~18us stall, waves not co-resident. Model says ~18-20us total.
// Per the skill's ablation discipline: this round launches THREE kernels
// sequentially, each a separate rocprof dispatch row:
//   1) crf_loads   -- exact 20-load burst only (+live-keeping reduce)
//   2) crf_compute -- exact CRF body, synthesized inputs, zero vmem
//   3) crf_main    -- R10 verbatim (runs LAST: overwrites ws garbage,
//                     output stays bit-exact)
//   4) crf_reduce  -- 2048 partials -> mean
// Interpretation matrix pre-committed in the journal.

#define LOG2E 1.4426950408889634f
#define LN2   0.6931471805599453f

constexpr int B = 8192;
constexpr int L = 1024;
constexpr int SEQS_PER_BLOCK = 4;   // 4 waves of 64 per block
constexpr int NBLK = B / SEQS_PER_BLOCK;  // 2048 partials

__device__ __forceinline__ float fexp2(float x) { return __builtin_amdgcn_exp2f(x); }
__device__ __forceinline__ float flog2(float x) { return __builtin_amdgcn_logf(x); }

__device__ __forceinline__ float f4get(const float4& v, int c) {
  return c == 0 ? v.x : (c == 1 ? v.y : (c == 2 ? v.z : v.w));
}
__device__ __forceinline__ int i4get(const int4& v, int c) {
  return c == 0 ? v.x : (c == 1 ? v.y : (c == 2 ? v.z : v.w));
}

__device__ __forceinline__ float mux3(float x0, float x1, float x2, int i) {
  return (i == 0) ? x0 : ((i == 1) ? x1 : x2);
}
// transitions[p][c] via cndmask chain (no dynamic register indexing)
__device__ __forceinline__ float trmux(const float* __restrict__ T2, int p, int c) {
  const float r0 = mux3(T2[0], T2[1], T2[2], c);
  const float r1 = mux3(T2[3], T2[4], T2[5], c);
  const float r2 = mux3(T2[6], T2[7], T2[8], c);
  return mux3(r0, r1, r2, p);
}

__device__ __forceinline__ void matmul3(float* __restrict__ D,
                                        const float* __restrict__ A,
                                        const float* __restrict__ Bm) {
  #pragma unroll
  for (int i = 0; i < 3; ++i)
    #pragma unroll
    for (int j = 0; j < 3; ++j)
      D[i * 3 + j] = A[i * 3 + 0] * Bm[0 * 3 + j] +
                     A[i * 3 + 1] * Bm[1 * 3 + j] +
                     A[i * 3 + 2] * Bm[2 * 3 + j];
}

// Exact power-of-2 renormalization: P *= 2^-ex, scale += ex.
__device__ __forceinline__ void renorm3(float* __restrict__ P, float& scale) {
  float m = P[0];
  #pragma unroll
  for (int e = 1; e < 9; ++e) m = fmaxf(m, P[e]);
  int ex;
  (void)frexpf(m, &ex);
  #pragma unroll
  for (int e = 0; e < 9; ++e) P[e] = ldexpf(P[e], -ex);
  scale += (float)ex;
}

// ---------------------------------------------------------------------------
// ABLATION A: the exact 20-load burst of crf_main, nothing else.
// Live-keeping: component-sum -> wave shfl reduce -> store (overwritten by C).
// ---------------------------------------------------------------------------
__global__ __launch_bounds__(256, 4) void crf_loads(
    const float* __restrict__ em, const float* __restrict__ mask,
    const float* __restrict__ trans, const int* __restrict__ tags,
    float* __restrict__ ws) {
  const int lane = threadIdx.x & 63;
  const int wid = threadIdx.x >> 6;
  const int b = blockIdx.x * SEQS_PER_BLOCK + wid;

  const float4* em4 = (const float4*)(em + (size_t)b * (L * 3)) + lane * 12;
  const float4* mk4 = (const float4*)(mask + (size_t)b * L) + lane * 4;
  const int4*   tg4 = (const int4*)(tags + (size_t)b * L) + lane * 4;

  float4 E[12];
  #pragma unroll
  for (int u = 0; u < 12; ++u) E[u] = em4[u];
  float4 MK[4];
  #pragma unroll
  for (int u = 0; u < 4; ++u) MK[u] = mk4[u];
  int4 TG[4];
  #pragma unroll
  for (int u = 0; u < 4; ++u) TG[u] = tg4[u];

  float s = trans[0];
  #pragma unroll
  for (int u = 0; u < 12; ++u) s += (E[u].x + E[u].y) + (E[u].z + E[u].w);
  #pragma unroll
  for (int u = 0; u < 4; ++u) s += (MK[u].x + MK[u].y) + (MK[u].z + MK[u].w);
  int si = 0;
  #pragma unroll
  for (int u = 0; u < 4; ++u) si += (TG[u].x + TG[u].y) + (TG[u].z + TG[u].w);
  s += (float)si;
  #pragma unroll
  for (int d = 1; d < 64; d <<= 1) s += __shfl_xor(s, d, 64);
  if (threadIdx.x == 0) ws[blockIdx.x] = s;   // garbage; C overwrites
}

// ---------------------------------------------------------------------------
// ABLATION B: the exact CRF body with synthesized inputs (zero vector mem).
// E/MK/TG built from ~50 VALU ops; everything downstream identical to C.
// ---------------------------------------------------------------------------
__global__ __launch_bounds__(256, 4) void crf_compute(
    const float* __restrict__ em, const float* __restrict__ mask,
    const float* __restrict__ trans, const int* __restrict__ tags,
    float* __restrict__ ws) {
  const int lane = threadIdx.x & 63;
  const int wid = threadIdx.x >> 6;
  const int b = blockIdx.x * SEQS_PER_BLOCK + wid;

  // ---- synthesized inputs (small values: exp2 stays in range) ----
  const float base = (float)((lane ^ (b & 63)) & 63) * 0.015625f - 0.5f;
  float4 E[12];
  #pragma unroll
  for (int u = 0; u < 12; ++u)
    E[u] = make_float4(fmaf(0.013f, (float)(4 * u + 0), base),
                       fmaf(-0.007f, (float)(4 * u + 1), base),
                       fmaf(0.011f, (float)(4 * u + 2), base),
                       fmaf(-0.005f, (float)(4 * u + 3), base));
  float4 MK[4];
  #pragma unroll
  for (int u = 0; u < 4; ++u) MK[u] = make_float4(1.f, 1.f, 1.f, 1.f);
  int4 TG[4];
  #pragma unroll
  for (int u = 0; u < 4; ++u)
    TG[u] = make_int4((lane + u) & 3, (lane + u + 1) & 3,
                      (lane + u + 2) & 3, (lane + u + 3) & 3);

  float T2[9], tk[9];
  #pragma unroll
  for (int e = 0; e < 9; ++e) {
    T2[e] = trans[e] * LOG2E;
    tk[e] = fexp2(T2[e]);
  }

  float P[9] = {1.f, 0.f, 0.f, 0.f, 1.f, 0.f, 0.f, 0.f, 1.f};
  float scale = 0.f, gold = 0.f;
  float a0 = 0.f, a1 = 0.f, a2 = 0.f;
  float e0_sel = 0.f, mk0 = 0.f;
  int tag0 = 0, prev = 0;

  #pragma unroll
  for (int s = 0; s < 16; ++s) {
    const float ev0 = f4get(E[(3 * s + 0) >> 2], (3 * s + 0) & 3) * LOG2E;
    const float ev1 = f4get(E[(3 * s + 1) >> 2], (3 * s + 1) & 3) * LOG2E;
    const float ev2 = f4get(E[(3 * s + 2) >> 2], (3 * s + 2) & 3) * LOG2E;
    const float m   = f4get(MK[s >> 2], s & 3);
    const int   cur = i4get(TG[s >> 2], s & 3);

    const float e = mux3(ev0, ev1, ev2, cur);
    if (s == 0) {
      e0_sel = e; mk0 = m; tag0 = cur;
    } else {
      gold = fmaf(trmux(T2, prev, cur) + e, m, gold);
    }
    prev = cur;

    const float w0 = fexp2(ev0);
    const float w1 = fexp2(ev1);
    const float w2 = fexp2(ev2);
    if (s == 0) { a0 = w0; a1 = w1; a2 = w2; }
    const bool act = (m > 0.f) && !(s == 0 && lane == 0);
    const float g  = act ? 1.f : 0.f;
    const float c1 = 1.f - g;
    const float u0 = w0 * g, u1 = w1 * g, u2 = w2 * g;
    float M[9];
    M[0] = fmaf(tk[0], u0, c1); M[1] = tk[1] * u1;           M[2] = tk[2] * u2;
    M[3] = tk[3] * u0;          M[4] = fmaf(tk[4], u1, c1);  M[5] = tk[5] * u2;
    M[6] = tk[6] * u0;          M[7] = tk[7] * u1;           M[8] = fmaf(tk[8], u2, c1);
    float N[9];
    matmul3(N, P, M);
    #pragma unroll
    for (int e2 = 0; e2 < 9; ++e2) P[e2] = N[e2];

    if (s == 7 || s == 15) renorm3(P, scale);
  }

  const int prevLast = __shfl_up(prev, 1);
  if (lane == 0) gold = fmaf(e0_sel, mk0, gold);
  else           gold = fmaf(trmux(T2, prevLast, tag0) + e0_sel, mk0, gold);
  #pragma unroll
  for (int d = 1; d < 64; d <<= 1) gold += __shfl_xor(gold, d, 64);

  #pragma unroll
  for (int d = 1; d < 64; d <<= 1) {
    float o[9];
    #pragma unroll
    for (int e = 0; e < 9; ++e) o[e] = __shfl_xor(P[e], d, 64);
    const float osc = __shfl_xor(scale, d, 64);
    const bool later = (lane & d) != 0;
    float A[9], Bm[9];
    #pragma unroll
    for (int e = 0; e < 9; ++e) {
      A[e]  = later ? o[e] : P[e];
      Bm[e] = later ? P[e] : o[e];
    }
    float N[9];
    matmul3(N, A, Bm);
    #pragma unroll
    for (int e = 0; e < 9; ++e) P[e] = N[e];
    scale += osc;
  }

  __shared__ float red[SEQS_PER_BLOCK];
  if (lane == 0) {
    const float z = a0 * (P[0] + P[1] + P[2]) +
                    a1 * (P[3] + P[4] + P[5]) +
                    a2 * (P[6] + P[7] + P[8]);
    red[wid] = LN2 * (scale + flog2(z) - gold);
  }
  __syncthreads();
  if (threadIdx.x == 0) {
    ws[blockIdx.x] = red[0] + red[1] + red[2] + red[3];  // garbage; C overwrites
  }
}

// ---------------------------------------------------------------------------
// C: the real kernel (R10 verbatim). Runs last -> ws correct.
// ---------------------------------------------------------------------------
__global__ __launch_bounds__(256, 4) void crf_main(
    const float* __restrict__ em, const float* __restrict__ mask,
    const float* __restrict__ trans, const int* __restrict__ tags,
    float* __restrict__ ws) {
  const int lane = threadIdx.x & 63;
  const int wid = threadIdx.x >> 6;
  const int b = blockIdx.x * SEQS_PER_BLOCK + wid;

  const float4* em4 = (const float4*)(em + (size_t)b * (L * 3)) + lane * 12;
  const float4* mk4 = (const float4*)(mask + (size_t)b * L) + lane * 4;
  const int4*   tg4 = (const int4*)(tags + (size_t)b * L) + lane * 4;

  float4 E[12];
  #pragma unroll
  for (int u = 0; u < 12; ++u) E[u] = em4[u];
  float4 MK[4];
  #pragma unroll
  for (int u = 0; u < 4; ++u) MK[u] = mk4[u];
  int4 TG[4];
  #pragma unroll
  for (int u = 0; u < 4; ++u) TG[u] = tg4[u];

  float T2[9], tk[9];
  #pragma unroll
  for (int e = 0; e < 9; ++e) {
    T2[e] = trans[e] * LOG2E;
    tk[e] = fexp2(T2[e]);
  }

  float P[9] = {1.f, 0.f, 0.f, 0.f, 1.f, 0.f, 0.f, 0.f, 1.f};
  float scale = 0.f, gold = 0.f;
  float a0 = 0.f, a1 = 0.f, a2 = 0.f;
  float e0_sel = 0.f, mk0 = 0.f;
  int tag0 = 0, prev = 0;

  #pragma unroll
  for (int s = 0; s < 16; ++s) {
    const float ev0 = f4get(E[(3 * s + 0) >> 2], (3 * s + 0) & 3) * LOG2E;
    const float ev1 = f4get(E[(3 * s + 1) >> 2], (3 * s + 1) & 3) * LOG2E;
    const float ev2 = f4get(E[(3 * s + 2) >> 2], (3 * s + 2) & 3) * LOG2E;
    const float m   = f4get(MK[s >> 2], s & 3);
    const int   cur = i4get(TG[s >> 2], s & 3);

    const float e = mux3(ev0, ev1, ev2, cur);
    if (s == 0) {
      e0_sel = e; mk0 = m; tag0 = cur;
    } else {
      gold = fmaf(trmux(T2, prev, cur) + e, m, gold);
    }
    prev = cur;

    const float w0 = fexp2(ev0);
    const float w1 = fexp2(ev1);
    const float w2 = fexp2(ev2);
    if (s == 0) { a0 = w0; a1 = w1; a2 = w2; }
    const bool act = (m > 0.f) && !(s == 0 && lane == 0);
    const float g  = act ? 1.f : 0.f;
    const float c1 = 1.f - g;
    const float u0 = w0 * g, u1 = w1 * g, u2 = w2 * g;
    float M[9];
    M[0] = fmaf(tk[0], u0, c1); M[1] = tk[1] * u1;           M[2] = tk[2] * u2;
    M[3] = tk[3] * u0;          M[4] = fmaf(tk[4], u1, c1);  M[5] = tk[5] * u2;
    M[6] = tk[6] * u0;          M[7] = tk[7] * u1;           M[8] = fmaf(tk[8], u2, c1);
    float N[9];
    matmul3(N, P, M);
    #pragma unroll
    for (int e2 = 0; e2 < 9; ++e2) P[e2] = N[e2];

    if (s == 7 || s == 15) renorm3(P, scale);
  }

  const int prevLast = __shfl_up(prev, 1);
  if (lane == 0) gold = fmaf(e0_sel, mk0, gold);
  else           gold = fmaf(trmux(T2, prevLast, tag0) + e0_sel, mk0, gold);
  #pragma unroll
  for (int d = 1; d < 64; d <<= 1) gold += __shfl_xor(gold, d, 64);

  #pragma unroll
  for (int d = 1; d < 64; d <<= 1) {
    float o[9];
    #pragma unroll
    for (int e = 0; e < 9; ++e) o[e] = __shfl_xor(P[e], d, 64);
    const float osc = __shfl_xor(scale, d, 64);
    const bool later = (lane & d) != 0;
    float A[9], Bm[9];
    #pragma unroll
    for (int e = 0; e < 9; ++e) {
      A[e]  = later ? o[e] : P[e];
      Bm[e] = later ? P[e] : o[e];
    }
    float N[9];
    matmul3(N, A, Bm);
    #pragma unroll
    for (int e = 0; e < 9; ++e) P[e] = N[e];
    scale += osc;
  }

  __shared__ float red[SEQS_PER_BLOCK];
  if (lane == 0) {
    const float z = a0 * (P[0] + P[1] + P[2]) +
                    a1 * (P[3] + P[4] + P[5]) +
                    a2 * (P[6] + P[7] + P[8]);
    red[wid] = LN2 * (scale + flog2(z) - gold);
  }
  __syncthreads();
  if (threadIdx.x == 0) {
    ws[blockIdx.x] = red[0] + red[1] + red[2] + red[3];
  }
}

// Reduce 2048 block partials -> mean. One block, no atomics.
__global__ __launch_bounds__(256) void crf_reduce(
    const float* __restrict__ ws, float* __restrict__ out) {
  const int t = threadIdx.x;
  const float4* w4 = (const float4*)ws;
  float4 v0 = w4[t];            // 256 threads x 2 float4 = 2048 floats
  float4 v1 = w4[256 + t];
  float s = (v0.x + v0.y) + (v0.z + v0.w) + (v1.x + v1.y) + (v1.z + v1.w);
  #pragma unroll
  for (int d = 1; d < 64; d <<= 1) s += __shfl_xor(s, d, 64);
  __shared__ float red[4];
  if ((t & 63) == 0) red[t >> 6] = s;
  __syncthreads();
  if (t == 0) out[0] = (red[0] + red[1] + red[2] + red[3]) * (1.0f / (float)B);
}

extern "C" void kernel_launch(void* const* d_in, const int* in_sizes, int n_in,
                              void* d_out, int out_size, void* d_ws, size_t ws_size,
                              hipStream_t stream) {
  const float* em    = (const float*)d_in[0];
  const float* mask  = (const float*)d_in[1];
  const float* trans = (const float*)d_in[2];
  const int*   tags  = (const int*)d_in[3];
  float* out = (float*)d_out;
  float* ws  = (float*)d_ws;

  // Ablation dispatches (results overwritten by crf_main):
  crf_loads<<<NBLK, 256, 0, stream>>>(em, mask, trans, tags, ws);
  crf_compute<<<NBLK, 256, 0, stream>>>(em, mask, trans, tags, ws);
  // Real kernel + reduction:
  crf_main<<<NBLK, 256, 0, stream>>>(em, mask, trans, tags, ws);
  crf_reduce<<<1, 256, 0, stream>>>(ws, out);
}

// Round 9
// 198.889 us; speedup vs baseline: 1.2026x; 1.2026x over previous
//
#include <hip/hip_runtime.h>

// LinearCRF: mean_b( logZ_b - gold_b ), B=8192, L=1024, S=3.
// Scaled linear-domain forward: lane owns a 16-step chunk, builds the 3x3
// transfer-matrix product in linear space with exact power-of-2 renorm;
// 6-stage ordered shfl_xor butterfly composes 64 chunks per wave
// (1 wave = 1 sequence). Gold score fused. Partials -> ws, tiny reduce.
// R12: ASM-FORCED LOAD BURST. R11 ablation: crf_loads (20-load burst
// alone) = 60us of the 65 (VALUBusy 2.5%); compute is cheap. Line count
// is minimal and R4 proved txn-coalescing doesn't help -> the wall is
// per-wave MLP: compiler re-serialized the burst into 4-5 dependent
// round trips (VGPR=60 proves it; 80 dest regs needed). launch_bounds
// hints (R7) and sched_barrier (R8) failed to stop the sinking. Fix:
// inline-asm global_load_dwordx4 cannot be sunk/split -- all 20 loads
// in flight, ONE s_waitcnt vmcnt(0) + sched_barrier(0) (rule #18).
// launch_bounds(256,3): ~168 VGPR budget, 3 waves/SIMD.

#define LOG2E 1.4426950408889634f
#define LN2   0.6931471805599453f

constexpr int B = 8192;
constexpr int L = 1024;
constexpr int SEQS_PER_BLOCK = 4;   // 4 waves of 64 per block
constexpr int NBLK = B / SEQS_PER_BLOCK;  // 2048 partials

__device__ __forceinline__ float fexp2(float x) { return __builtin_amdgcn_exp2f(x); }
__device__ __forceinline__ float flog2(float x) { return __builtin_amdgcn_logf(x); }

// Force-materialized 16B load: compiler cannot sink/split/serialize this.
#define GLOAD16(dst, base, OFF)                                        \
  asm volatile("global_load_dwordx4 %0, %1, off offset:" #OFF          \
               : "=v"(dst) : "v"(base))

__device__ __forceinline__ float f4get(const float4& v, int c) {
  return c == 0 ? v.x : (c == 1 ? v.y : (c == 2 ? v.z : v.w));
}
__device__ __forceinline__ int i4get(const int4& v, int c) {
  return c == 0 ? v.x : (c == 1 ? v.y : (c == 2 ? v.z : v.w));
}

__device__ __forceinline__ float mux3(float x0, float x1, float x2, int i) {
  return (i == 0) ? x0 : ((i == 1) ? x1 : x2);
}
// transitions[p][c] via cndmask chain (no dynamic register indexing)
__device__ __forceinline__ float trmux(const float* __restrict__ T2, int p, int c) {
  const float r0 = mux3(T2[0], T2[1], T2[2], c);
  const float r1 = mux3(T2[3], T2[4], T2[5], c);
  const float r2 = mux3(T2[6], T2[7], T2[8], c);
  return mux3(r0, r1, r2, p);
}

__device__ __forceinline__ void matmul3(float* __restrict__ D,
                                        const float* __restrict__ A,
                                        const float* __restrict__ Bm) {
  #pragma unroll
  for (int i = 0; i < 3; ++i)
    #pragma unroll
    for (int j = 0; j < 3; ++j)
      D[i * 3 + j] = A[i * 3 + 0] * Bm[0 * 3 + j] +
                     A[i * 3 + 1] * Bm[1 * 3 + j] +
                     A[i * 3 + 2] * Bm[2 * 3 + j];
}

// Exact power-of-2 renormalization: P *= 2^-ex, scale += ex.
__device__ __forceinline__ void renorm3(float* __restrict__ P, float& scale) {
  float m = P[0];
  #pragma unroll
  for (int e = 1; e < 9; ++e) m = fmaxf(m, P[e]);
  int ex;
  (void)frexpf(m, &ex);
  #pragma unroll
  for (int e = 0; e < 9; ++e) P[e] = ldexpf(P[e], -ex);
  scale += (float)ex;
}

__global__ __launch_bounds__(256, 3) void crf_main(
    const float* __restrict__ em, const float* __restrict__ mask,
    const float* __restrict__ trans, const int* __restrict__ tags,
    float* __restrict__ ws) {
  const int lane = threadIdx.x & 63;
  const int wid = threadIdx.x >> 6;
  const int b = blockIdx.x * SEQS_PER_BLOCK + wid;

  const float4* em4 = (const float4*)(em + (size_t)b * (L * 3)) + lane * 12;
  const float4* mk4 = (const float4*)(mask + (size_t)b * L) + lane * 4;
  const int4*   tg4 = (const int4*)(tags + (size_t)b * L) + lane * 4;

  // ---- 20 loads, ALL in flight before one vmcnt(0): forced via asm ----
  float4 E[12];
  GLOAD16(E[0],  em4, 0);
  GLOAD16(E[1],  em4, 16);
  GLOAD16(E[2],  em4, 32);
  GLOAD16(E[3],  em4, 48);
  GLOAD16(E[4],  em4, 64);
  GLOAD16(E[5],  em4, 80);
  GLOAD16(E[6],  em4, 96);
  GLOAD16(E[7],  em4, 112);
  GLOAD16(E[8],  em4, 128);
  GLOAD16(E[9],  em4, 144);
  GLOAD16(E[10], em4, 160);
  GLOAD16(E[11], em4, 176);
  float4 MK[4];
  GLOAD16(MK[0], mk4, 0);
  GLOAD16(MK[1], mk4, 16);
  GLOAD16(MK[2], mk4, 32);
  GLOAD16(MK[3], mk4, 48);
  int4 TG[4];
  GLOAD16(TG[0], tg4, 0);
  GLOAD16(TG[1], tg4, 16);
  GLOAD16(TG[2], tg4, 32);
  GLOAD16(TG[3], tg4, 48);

  // Transitions: log2 domain + linear form (uniform -> scalar loads),
  // computed while the burst is in flight.
  float T2[9], tk[9];
  #pragma unroll
  for (int e = 0; e < 9; ++e) {
    T2[e] = trans[e] * LOG2E;
    tk[e] = fexp2(T2[e]);
  }

  // Hardware wait for the asm loads; fence VALU motion (rule #18).
  asm volatile("s_waitcnt vmcnt(0)" ::: "memory");
  __builtin_amdgcn_sched_barrier(0);

  float P[9] = {1.f, 0.f, 0.f, 0.f, 1.f, 0.f, 0.f, 0.f, 1.f};
  float scale = 0.f, gold = 0.f;
  float a0 = 0.f, a1 = 0.f, a2 = 0.f;   // step-0 linear emissions (lane 0)
  float e0_sel = 0.f, mk0 = 0.f;        // deferred step-0 gold term
  int tag0 = 0, prev = 0;

  #pragma unroll
  for (int s = 0; s < 16; ++s) {
    const float ev0 = f4get(E[(3 * s + 0) >> 2], (3 * s + 0) & 3) * LOG2E;
    const float ev1 = f4get(E[(3 * s + 1) >> 2], (3 * s + 1) & 3) * LOG2E;
    const float ev2 = f4get(E[(3 * s + 2) >> 2], (3 * s + 2) & 3) * LOG2E;
    const float m   = f4get(MK[s >> 2], s & 3);
    const int   cur = i4get(TG[s >> 2], s & 3);

    // ---- gold score (log2 domain) ----
    const float e = mux3(ev0, ev1, ev2, cur);
    if (s == 0) {
      e0_sel = e; mk0 = m; tag0 = cur;   // cross-lane prev tag fixed up later
    } else {
      gold = fmaf(trmux(T2, prev, cur) + e, m, gold);
    }
    prev = cur;

    // ---- matrix step (linear domain): M = act ? tk.*w : I ----
    const float w0 = fexp2(ev0);
    const float w1 = fexp2(ev1);
    const float w2 = fexp2(ev2);
    if (s == 0) { a0 = w0; a1 = w1; a2 = w2; }
    const bool act = (m > 0.f) && !(s == 0 && lane == 0);  // t=0 is alpha0
    const float g  = act ? 1.f : 0.f;
    const float c1 = 1.f - g;
    const float u0 = w0 * g, u1 = w1 * g, u2 = w2 * g;
    float M[9];
    M[0] = fmaf(tk[0], u0, c1); M[1] = tk[1] * u1;           M[2] = tk[2] * u2;
    M[3] = tk[3] * u0;          M[4] = fmaf(tk[4], u1, c1);  M[5] = tk[5] * u2;
    M[6] = tk[6] * u0;          M[7] = tk[7] * u1;           M[8] = fmaf(tk[8], u2, c1);
    float N[9];
    matmul3(N, P, M);
    #pragma unroll
    for (int e2 = 0; e2 < 9; ++e2) P[e2] = N[e2];

    if (s == 7 || s == 15) renorm3(P, scale);  // bound fp32 range
  }

  // ---- deferred step-0 gold term (needs previous lane's last tag) ----
  const int prevLast = __shfl_up(prev, 1);
  if (lane == 0) gold = fmaf(e0_sel, mk0, gold);
  else           gold = fmaf(trmux(T2, prevLast, tag0) + e0_sel, mk0, gold);
  #pragma unroll
  for (int d = 1; d < 64; d <<= 1) gold += __shfl_xor(gold, d, 64);

  // ---- ordered butterfly combine (entries <= 3^6 = 729: no renorm needed) ----
  #pragma unroll
  for (int d = 1; d < 64; d <<= 1) {
    float o[9];
    #pragma unroll
    for (int e = 0; e < 9; ++e) o[e] = __shfl_xor(P[e], d, 64);
    const float osc = __shfl_xor(scale, d, 64);
    const bool later = (lane & d) != 0;  // self covers the later time segment
    float A[9], Bm[9];
    #pragma unroll
    for (int e = 0; e < 9; ++e) {
      A[e]  = later ? o[e] : P[e];
      Bm[e] = later ? P[e] : o[e];
    }
    float N[9];
    matmul3(N, A, Bm);
    #pragma unroll
    for (int e = 0; e < 9; ++e) P[e] = N[e];
    scale += osc;
  }

  // ---- finalize + block partial -> workspace (no atomic) ----
  __shared__ float red[SEQS_PER_BLOCK];
  if (lane == 0) {
    const float z = a0 * (P[0] + P[1] + P[2]) +
                    a1 * (P[3] + P[4] + P[5]) +
                    a2 * (P[6] + P[7] + P[8]);
    red[wid] = LN2 * (scale + flog2(z) - gold);
  }
  __syncthreads();
  if (threadIdx.x == 0) {
    ws[blockIdx.x] = red[0] + red[1] + red[2] + red[3];
  }
}

// Reduce 2048 block partials -> mean. One block, no atomics.
__global__ __launch_bounds__(256) void crf_reduce(
    const float* __restrict__ ws, float* __restrict__ out) {
  const int t = threadIdx.x;
  const float4* w4 = (const float4*)ws;
  float4 v0 = w4[t];            // 256 threads x 2 float4 = 2048 floats
  float4 v1 = w4[256 + t];
  float s = (v0.x + v0.y) + (v0.z + v0.w) + (v1.x + v1.y) + (v1.z + v1.w);
  #pragma unroll
  for (int d = 1; d < 64; d <<= 1) s += __shfl_xor(s, d, 64);
  __shared__ float red[4];
  if ((t & 63) == 0) red[t >> 6] = s;
  __syncthreads();
  if (t == 0) out[0] = (red[0] + red[1] + red[2] + red[3]) * (1.0f / (float)B);
}

extern "C" void kernel_launch(void* const* d_in, const int* in_sizes, int n_in,
                              void* d_out, int out_size, void* d_ws, size_t ws_size,
                              hipStream_t stream) {
  const float* em    = (const float*)d_in[0];
  const float* mask  = (const float*)d_in[1];
  const float* trans = (const float*)d_in[2];
  const int*   tags  = (const int*)d_in[3];
  float* out = (float*)d_out;
  float* ws  = (float*)d_ws;

  crf_main<<<NBLK, 256, 0, stream>>>(em, mask, trans, tags, ws);
  crf_reduce<<<1, 256, 0, stream>>>(ws, out);
}